// Round 1
// 507.845 us; speedup vs baseline: 1.0143x; 1.0143x over previous
//
#include <hip/hip_runtime.h>
#include <math.h>

#define NB 8
#define IC 256
#define CC 64
#define HH 128
#define WW 128
#define NN (HH*WW)      // 16384
#define NKW 64          // k-chunks for gramW (8192/64 = 128 k per chunk)
#define NKC 64          // n-chunks for gramC (16384/64 = 256 n per chunk)

// ---------------- workspace layout (floats) ----------------
// pW (NB*NKW*16384 = 8.4M floats) is aliased onto the s region: pW is dead
// after k_redW, and k_co (which runs later) overwrites every element of s.
static constexpr size_t SZ_INP  = (size_t)NB * CC * NN;            // 8,388,608
static constexpr size_t OFF_INP = 0;
static constexpr size_t OFF_S   = OFF_INP + SZ_INP;                // s AND pW (aliased)
static constexpr size_t OFF_PC  = OFF_S + SZ_INP;                  // pC: NB*NKC*4096 = 2,097,152
static constexpr size_t OFF_TW  = OFF_PC + (size_t)NB * NKC * 4096;
static constexpr size_t OFF_TC  = OFF_TW + (size_t)NB * 16384;
static constexpr size_t OFF_WT  = OFF_TC + (size_t)NB * 4096;      // w_in_t [256 i][64 o]
static constexpr size_t OFF_WOT = OFF_WT + 16384;                  // w_out_t [64 c][256 o]

// ---------------- tiny transpose of both weight matrices ----------------
__global__ __launch_bounds__(256) void k_wt(
    const float* __restrict__ w_in, const float* __restrict__ w_out,
    float* __restrict__ w_in_t, float* __restrict__ w_out_t)
{
    const int idx = blockIdx.x * 256 + threadIdx.x;   // 0..32767
    if (idx < 16384) {
        const int o = idx & 63, i = idx >> 6;         // w_in_t[i][o] = w_in[o][i]
        w_in_t[idx] = w_in[o * IC + i];
    } else {
        const int j = idx - 16384;
        const int o = j & 255, c = j >> 8;            // w_out_t[c][o] = w_out[o][c]
        w_out_t[j] = w_out[o * CC + c];
    }
}

// ---------------- inconv: inp[b,o,n] = sum_i w_in[o,i]*x[b,i,n] + b_in[o] ----------------
// grid (NN/128, NB), block 256; 64o x 128n tile; 4o x 8n per thread (32 FMA / 3 LDS reads)
// LDS strides padded (68/132) -> conflict-free staging writes
__global__ __launch_bounds__(256) void k_inconv(
    const float* __restrict__ x, const float* __restrict__ wt,
    const float* __restrict__ b_in, float* __restrict__ inp)
{
    __shared__ float wl[64 * 68];    // [i_local][o], stride 68
    __shared__ float xs[64 * 132];   // [i_local][n], stride 132
    const int b  = blockIdx.y;
    const int n0 = blockIdx.x * 128;
    const int t  = threadIdx.x;
    const int o4 = (t >> 4) * 4;     // 16 groups * 4 = 64 o
    const int n4 = (t & 15) * 4;     // two quads: n4 and n4+64

    float acc[4][8];
#pragma unroll
    for (int p = 0; p < 4; p++)
#pragma unroll
        for (int q = 0; q < 8; q++) acc[p][q] = 0.f;

    const int sr = t >> 2, sc = (t & 3) * 4;   // staging: row sr, 16-float strided quads
    for (int i0 = 0; i0 < IC; i0 += 64) {
        __syncthreads();
        {
            const float* src = x + ((size_t)b * IC + i0 + sr) * NN + n0;
            float* dst = xs + sr * 132;
#pragma unroll
            for (int k = 0; k < 8; k++)
                *(float4*)(dst + sc + 16 * k) = *(const float4*)(src + sc + 16 * k);
            const float* wsrc = wt + (size_t)(i0 + sr) * 64;
            float* wdst = wl + sr * 68;
#pragma unroll
            for (int k = 0; k < 4; k++)
                *(float4*)(wdst + sc + 16 * k) = *(const float4*)(wsrc + sc + 16 * k);
        }
        __syncthreads();
#pragma unroll 4
        for (int i = 0; i < 64; i++) {
            const float4 a4 = *(const float4*)(wl + i * 68 + o4);
            const float4 xa = *(const float4*)(xs + i * 132 + n4);
            const float4 xb = *(const float4*)(xs + i * 132 + 64 + n4);
            const float av[4] = {a4.x, a4.y, a4.z, a4.w};
            const float xv[8] = {xa.x, xa.y, xa.z, xa.w, xb.x, xb.y, xb.z, xb.w};
#pragma unroll
            for (int p = 0; p < 4; p++)
#pragma unroll
                for (int q = 0; q < 8; q++) acc[p][q] += av[p] * xv[q];
        }
    }
#pragma unroll
    for (int p = 0; p < 4; p++) {
        const int oo = o4 + p;
        const float bo = b_in[oo];
        float* base = inp + ((size_t)b * CC + oo) * NN + n0;
        *(float4*)(base + n4) = make_float4(acc[p][0] + bo, acc[p][1] + bo,
                                            acc[p][2] + bo, acc[p][3] + bo);
        *(float4*)(base + 64 + n4) = make_float4(acc[p][4] + bo, acc[p][5] + bo,
                                                 acc[p][6] + bo, acc[p][7] + bo);
    }
}

// ---------------- gram W partials: NKW=64 chunks (2 blocks/CU) ----------------
__global__ __launch_bounds__(256) void k_gramW(const float* __restrict__ inp, float* __restrict__ pW)
{
    __shared__ float xs[8 * 128];
    const int b = blockIdx.y, kc = blockIdx.x;
    const int t = threadIdx.x, tx = t & 15, ty = t >> 4;
    const float* Xb = inp + (size_t)b * CC * NN;
    const int k0 = kc * ((CC * HH) / NKW);   // 128 k per chunk

    float acc[8][8];
#pragma unroll
    for (int i = 0; i < 8; i++)
#pragma unroll
        for (int j = 0; j < 8; j++) acc[i][j] = 0.f;

    for (int kk = k0; kk < k0 + (CC * HH) / NKW; kk += 8) {
        __syncthreads();
        for (int idx = t; idx < 1024; idx += 256)
            xs[idx] = Xb[((size_t)kk + (idx >> 7)) * WW + (idx & 127)];
        __syncthreads();
#pragma unroll
        for (int k = 0; k < 8; k++) {
            const float* row = xs + k * 128;
            float4 t0 = *(const float4*)(row + ty * 8);
            float4 t1 = *(const float4*)(row + ty * 8 + 4);
            float4 u0 = *(const float4*)(row + tx * 8);
            float4 u1 = *(const float4*)(row + tx * 8 + 4);
            float av[8] = {t0.x, t0.y, t0.z, t0.w, t1.x, t1.y, t1.z, t1.w};
            float bv[8] = {u0.x, u0.y, u0.z, u0.w, u1.x, u1.y, u1.z, u1.w};
#pragma unroll
            for (int i = 0; i < 8; i++)
#pragma unroll
                for (int j = 0; j < 8; j++) acc[i][j] += av[i] * bv[j];
        }
    }
    float* dst = pW + ((size_t)b * NKW + kc) * 16384;
#pragma unroll
    for (int i = 0; i < 8; i++)
#pragma unroll
        for (int j = 0; j < 8; j += 4) {
            float4 v = make_float4(acc[i][j], acc[i][j + 1], acc[i][j + 2], acc[i][j + 3]);
            *(float4*)(dst + (ty * 8 + i) * 128 + tx * 8 + j) = v;
        }
}

__global__ __launch_bounds__(256) void k_redW(const float* __restrict__ pW, float* __restrict__ Tw)
{
    const int b = blockIdx.y;
    const int idx = blockIdx.x * 256 + threadIdx.x;
    const float* p = pW + (size_t)b * NKW * 16384 + idx;
    float acc = 0.f;
#pragma unroll
    for (int k = 0; k < NKW; k++) acc += p[(size_t)k * 16384];
    Tw[(size_t)b * 16384 + idx] = acc;
}

__global__ __launch_bounds__(128) void k_softW(float* __restrict__ Tw)
{
    const int b = blockIdx.x, v = threadIdx.x;
    float* S = Tw + (size_t)b * 16384;
    float m = -3.4e38f;
    for (int w = 0; w < 128; w++) m = fmaxf(m, S[w * 128 + v]);
    float sum = 0.f;
    for (int w = 0; w < 128; w++) { float e = __expf(S[w * 128 + v] - m); sum += e; S[w * 128 + v] = e; }
    const float inv = 1.f / sum;
    for (int w = 0; w < 128; w++) S[w * 128 + v] *= inv;
}

// ---------------- gram C partials: transposed LDS tile [n][c], NKC=64 ----------------
__global__ __launch_bounds__(256) void k_gramC(const float* __restrict__ inp, float* __restrict__ pC)
{
    __shared__ float xt[32 * 68];   // [n_local][c], stride 68
    const int b = blockIdx.y, nc = blockIdx.x;
    const int t = threadIdx.x, tx = t & 15, ty = t >> 4;
    const float* ip = inp + (size_t)b * CC * NN;
    const int n0 = nc * (NN / NKC);          // 256-wide n chunk

    float acc[4][4];
#pragma unroll
    for (int i = 0; i < 4; i++)
#pragma unroll
        for (int j = 0; j < 4; j++) acc[i][j] = 0.f;

    const int scc = t >> 2;                  // c row 0..63
    const int sn  = (t & 3) * 8;             // n offset 0,8,16,24

    for (int nt = 0; nt < NN / NKC; nt += 32) {
        __syncthreads();
        {
            const float* src = ip + (size_t)scc * NN + n0 + nt + sn;
            float v[8];
            *(float4*)(v)     = *(const float4*)(src);
            *(float4*)(v + 4) = *(const float4*)(src + 4);
#pragma unroll
            for (int j = 0; j < 8; j++) xt[(sn + j) * 68 + scc] = v[j];
        }
        __syncthreads();
#pragma unroll 8
        for (int nn = 0; nn < 32; nn++) {
            const float4 a4 = *(const float4*)(xt + nn * 68 + ty * 4);
            const float4 e4 = *(const float4*)(xt + nn * 68 + tx * 4);
            const float av[4] = {a4.x, a4.y, a4.z, a4.w};
            const float ev[4] = {e4.x, e4.y, e4.z, e4.w};
#pragma unroll
            for (int i = 0; i < 4; i++)
#pragma unroll
                for (int j = 0; j < 4; j++) acc[i][j] += av[i] * ev[j];
        }
    }
    float* dst = pC + ((size_t)b * NKC + nc) * 4096;
#pragma unroll
    for (int i = 0; i < 4; i++) {
        float4 v = make_float4(acc[i][0], acc[i][1], acc[i][2], acc[i][3]);
        *(float4*)(dst + (ty * 4 + i) * 64 + tx * 4) = v;
    }
}

__global__ __launch_bounds__(256) void k_redC(const float* __restrict__ pC, float* __restrict__ Tc)
{
    const int b = blockIdx.y;
    const int idx = blockIdx.x * 256 + threadIdx.x;
    const float* p = pC + (size_t)b * NKC * 4096 + idx;
    float acc = 0.f;
#pragma unroll
    for (int k = 0; k < NKC; k++) acc += p[(size_t)k * 4096];
    Tc[(size_t)b * 4096 + idx] = acc;
}

__global__ __launch_bounds__(64) void k_softC(float* __restrict__ Tc)
{
    const int b = blockIdx.x, d = threadIdx.x;
    float* S = Tc + (size_t)b * 4096;
    float m = -3.4e38f;
    for (int c = 0; c < 64; c++) m = fmaxf(m, S[c * 64 + d]);
    float sum = 0.f;
    for (int c = 0; c < 64; c++) { float e = __expf(S[c * 64 + d] - m); sum += e; S[c * 64 + d] = e; }
    const float inv = 1.f / sum;
    for (int c = 0; c < 64; c++) S[c * 64 + d] *= inv;
}

// ---------------- Co: s_flat[b][n*64+d] = detal * sum_c inp[b,c,n]*Tc[c,d] ----------------
// grid (NN/128, NB), block 256; 64d x 128n tile; 8n x 4d per thread
__global__ __launch_bounds__(256) void k_co(
    const float* __restrict__ inp, const float* __restrict__ Tc,
    const float* __restrict__ detal, float* __restrict__ s)
{
    __shared__ float tc[64 * 68];    // [c][d], stride 68
    __shared__ float xs[64 * 132];   // [c][n], stride 132
    const int b  = blockIdx.y;
    const int n0 = blockIdx.x * 128;
    const int t  = threadIdx.x;
    const int d4 = (t & 15) * 4;
    const int g8 = (t >> 4) * 8;     // 16 groups * 8 = 128 n

    {
        const int sr = t >> 2, sc = (t & 3) * 4;
        const float* src = inp + ((size_t)b * CC + sr) * NN + n0;
        float* dst = xs + sr * 132;
#pragma unroll
        for (int k = 0; k < 8; k++)
            *(float4*)(dst + sc + 16 * k) = *(const float4*)(src + sc + 16 * k);
        const float* tsrc = Tc + (size_t)b * 4096 + sr * 64;
        float* tdst = tc + sr * 68;
#pragma unroll
        for (int k = 0; k < 4; k++)
            *(float4*)(tdst + sc + 16 * k) = *(const float4*)(tsrc + sc + 16 * k);
    }
    __syncthreads();

    float acc[8][4];   // [n][d]
#pragma unroll
    for (int i = 0; i < 8; i++)
#pragma unroll
        for (int j = 0; j < 4; j++) acc[i][j] = 0.f;

#pragma unroll 4
    for (int c = 0; c < 64; c++) {
        const float4 t4 = *(const float4*)(tc + c * 68 + d4);
        const float4 xa = *(const float4*)(xs + c * 132 + g8);
        const float4 xb = *(const float4*)(xs + c * 132 + g8 + 4);
        const float xv[8] = {xa.x, xa.y, xa.z, xa.w, xb.x, xb.y, xb.z, xb.w};
        const float tv[4] = {t4.x, t4.y, t4.z, t4.w};
#pragma unroll
        for (int i = 0; i < 8; i++)
#pragma unroll
            for (int j = 0; j < 4; j++) acc[i][j] += xv[i] * tv[j];
    }
    const float scl = detal[0];
    float* sb = s + (size_t)b * CC * NN + (size_t)n0 * 64;
#pragma unroll
    for (int i = 0; i < 8; i++) {
        float4 v = make_float4(acc[i][0] * scl, acc[i][1] * scl,
                               acc[i][2] * scl, acc[i][3] * scl);
        *(float4*)(sb + (size_t)(g8 + i) * 64 + d4) = v;
    }
}

// ---------------- Wo (==Ho): s[b,c,h,v] += 2*detal * sum_w inp[b,c,h,w]*Tw[w,v] ----------------
// grid (CC, 2 h-chunks, NB), block 256; Tw read straight from L1/L2 (512B coalesced/wave),
// 64 h-rows staged in LDS (34 KB -> 4 blocks/CU); 8h x 4v per thread (32 FMA per Tw float4)
__global__ __launch_bounds__(256) void k_wo(
    const float* __restrict__ inp, const float* __restrict__ Tw,
    const float* __restrict__ detal, float* __restrict__ s)
{
    __shared__ float rs[64 * 132];   // [h_local][w], stride 132
    const int b = blockIdx.z, hc = blockIdx.y, c = blockIdx.x;
    const int t = threadIdx.x;
    const int v4 = (t & 31) * 4;     // 32 groups * 4 = 128 v
    const int rg = t >> 5;           // 0..7, 8 h-rows each
    const int h0 = hc * 64;

    {
        const int sr = t >> 2, sc = (t & 3) * 4;
        const float* ip = inp + ((size_t)b * CC + c) * NN + (size_t)(h0 + sr) * WW;
        float* dst = rs + sr * 132;
#pragma unroll
        for (int k = 0; k < 8; k++)
            *(float4*)(dst + sc + 16 * k) = *(const float4*)(ip + sc + 16 * k);
    }
    __syncthreads();

    float acc[8][4];
#pragma unroll
    for (int i = 0; i < 8; i++)
#pragma unroll
        for (int j = 0; j < 4; j++) acc[i][j] = 0.f;

    const float* twp = Tw + (size_t)b * 16384 + v4;
    const float* rp  = rs + (rg * 8) * 132;
#pragma unroll 4
    for (int w = 0; w < 128; w++) {
        const float4 tv = *(const float4*)(twp + w * 128);
#pragma unroll
        for (int i = 0; i < 8; i++) {
            const float a = rp[i * 132 + w];
            acc[i][0] += a * tv.x; acc[i][1] += a * tv.y;
            acc[i][2] += a * tv.z; acc[i][3] += a * tv.w;
        }
    }
    const float sc2 = 2.0f * detal[0];
    float* sp = s + ((size_t)b * CC + c) * NN + (size_t)h0 * WW;
#pragma unroll
    for (int i = 0; i < 8; i++) {
        float* p = sp + (size_t)(rg * 8 + i) * WW + v4;
        float4 cur = *(const float4*)p;
        cur.x += sc2 * acc[i][0]; cur.y += sc2 * acc[i][1];
        cur.z += sc2 * acc[i][2]; cur.w += sc2 * acc[i][3];
        *(float4*)p = cur;
    }
}

// ---------------- outconv: out[b,o,n] = sum_c w_out[o,c]*s[b,c,n] + b_out[o] + x[b,o,n] ----------------
// grid (NN/64, 2 o-chunks, NB), block 256; 128o x 64n tile; 8o x 4n per thread
__global__ __launch_bounds__(256) void k_outconv(
    const float* __restrict__ s, const float* __restrict__ wot,
    const float* __restrict__ b_out, const float* __restrict__ x,
    float* __restrict__ outp)
{
    __shared__ float wl[64 * 132];  // [c][o_local 128], stride 132
    __shared__ float ss[64 * 68];   // [c][n 64], stride 68
    const int b  = blockIdx.z;
    const int o0 = blockIdx.y * 128;
    const int n0 = blockIdx.x * 64;
    const int t  = threadIdx.x;
    const int o8 = (t >> 4) * 8;    // 16 groups * 8 = 128 o
    const int n4 = (t & 15) * 4;

    {
        const int sr = t >> 2, sc = (t & 3) * 4;
        const float* src = s + ((size_t)b * CC + sr) * NN + n0;
        float* dst = ss + sr * 68;
#pragma unroll
        for (int k = 0; k < 4; k++)
            *(float4*)(dst + sc + 16 * k) = *(const float4*)(src + sc + 16 * k);
        const float* wsrc = wot + (size_t)sr * IC + o0;
        float* wdst = wl + sr * 132;
#pragma unroll
        for (int k = 0; k < 8; k++)
            *(float4*)(wdst + sc + 16 * k) = *(const float4*)(wsrc + sc + 16 * k);
    }
    __syncthreads();

    float acc[8][4];   // [o][n]
#pragma unroll
    for (int i = 0; i < 8; i++)
#pragma unroll
        for (int j = 0; j < 4; j++) acc[i][j] = 0.f;

#pragma unroll 4
    for (int c = 0; c < 64; c++) {
        const float4 s4 = *(const float4*)(ss + c * 68 + n4);
        const float4 wa = *(const float4*)(wl + c * 132 + o8);
        const float4 wb = *(const float4*)(wl + c * 132 + o8 + 4);
        const float wv[8] = {wa.x, wa.y, wa.z, wa.w, wb.x, wb.y, wb.z, wb.w};
        const float sv[4] = {s4.x, s4.y, s4.z, s4.w};
#pragma unroll
        for (int i = 0; i < 8; i++)
#pragma unroll
            for (int j = 0; j < 4; j++) acc[i][j] += wv[i] * sv[j];
    }

#pragma unroll
    for (int i = 0; i < 8; i++) {
        const int oo = o0 + o8 + i;
        const float bo = b_out[oo];
        const float4 xv = *(const float4*)(x + ((size_t)b * IC + oo) * NN + n0 + n4);
        float4 v = make_float4(acc[i][0] + bo + xv.x, acc[i][1] + bo + xv.y,
                               acc[i][2] + bo + xv.z, acc[i][3] + bo + xv.w);
        *(float4*)(outp + ((size_t)b * IC + oo) * NN + n0 + n4) = v;
    }
}

extern "C" void kernel_launch(void* const* d_in, const int* in_sizes, int n_in,
                              void* d_out, int out_size, void* d_ws, size_t ws_size,
                              hipStream_t stream)
{
    const float* x     = (const float*)d_in[0];
    const float* w_in  = (const float*)d_in[1];
    const float* b_in  = (const float*)d_in[2];
    const float* w_out = (const float*)d_in[3];
    const float* b_out = (const float*)d_in[4];
    const float* detal = (const float*)d_in[5];
    float* out = (float*)d_out;

    float* ws   = (float*)d_ws;
    float* inp  = ws + OFF_INP;
    float* s    = ws + OFF_S;
    float* pW   = ws + OFF_S;      // aliased with s (pW dead before k_co writes s)
    float* pC   = ws + OFF_PC;
    float* Tw   = ws + OFF_TW;
    float* Tc   = ws + OFF_TC;
    float* wt   = ws + OFF_WT;
    float* wot  = ws + OFF_WOT;

    k_wt     <<<dim3(128),              256, 0, stream>>>(w_in, w_out, wt, wot);
    k_inconv <<<dim3(NN / 128, NB),     256, 0, stream>>>(x, wt, b_in, inp);
    k_gramW  <<<dim3(NKW, NB),          256, 0, stream>>>(inp, pW);
    k_redW   <<<dim3(64, NB),           256, 0, stream>>>(pW, Tw);
    k_softW  <<<dim3(NB),               128, 0, stream>>>(Tw);
    k_gramC  <<<dim3(NKC, NB),          256, 0, stream>>>(inp, pC);
    k_redC   <<<dim3(16, NB),           256, 0, stream>>>(pC, Tc);
    k_softC  <<<dim3(NB),                64, 0, stream>>>(Tc);
    k_co     <<<dim3(NN / 128, NB),     256, 0, stream>>>(inp, Tc, detal, s);
    k_wo     <<<dim3(CC, 2, NB),        256, 0, stream>>>(inp, Tw, detal, s);
    k_outconv<<<dim3(NN / 64, 2, NB),   256, 0, stream>>>(s, wot, b_out, x, out);
}